// Round 1
// baseline (2699.715 us; speedup 1.0000x reference)
//
#include <hip/hip_runtime.h>
#include <math.h>

#define C_ 3
#define T_ 30
#define V_ 14
#define E_ 64
#define H_ 4
#define D_ 16
#define NC_ 7

// ---------------------------------------------------------------------------
// Setup: collapse the linear front-end into small tables in ws:
//   tab[0..191]     A_j[c][e]   = je_w @ P0
//   tab[192..383]   A_v[c][e]   = ve_w @ P0
//   tab[384..1279]  jproj[v][e] = joint_emb @ P1
//   tab[1280..3199] fprojb[t][e]= frame_emb @ P2 + proj_b + (je_b+ve_b) @ P0
// where P0/P1/P2 = proj_w rows [0:64)/[64:128)/[128:192)
// ---------------------------------------------------------------------------
__global__ void k_setup(const float* __restrict__ je_w, const float* __restrict__ je_b,
                        const float* __restrict__ ve_w, const float* __restrict__ ve_b,
                        const float* __restrict__ joint_emb, const float* __restrict__ frame_emb,
                        const float* __restrict__ proj_w, const float* __restrict__ proj_b,
                        float* __restrict__ tab) {
    int e = threadIdx.x;  // 64 threads
    for (int c = 0; c < C_; ++c) {
        float aj = 0.f, av = 0.f;
        for (int i = 0; i < E_; ++i) {
            float p0 = proj_w[i * E_ + e];
            aj += je_w[c * E_ + i] * p0;
            av += ve_w[c * E_ + i] * p0;
        }
        tab[c * E_ + e] = aj;
        tab[192 + c * E_ + e] = av;
    }
    for (int v = 0; v < V_; ++v) {
        float s = 0.f;
        for (int i = 0; i < E_; ++i) s += joint_emb[v * E_ + i] * proj_w[(64 + i) * E_ + e];
        tab[384 + v * E_ + e] = s;
    }
    float bias = proj_b[e];
    for (int i = 0; i < E_; ++i) bias += (je_b[i] + ve_b[i]) * proj_w[i * E_ + e];
    for (int t = 0; t < T_; ++t) {
        float s = bias;
        for (int i = 0; i < E_; ++i) s += frame_emb[t * E_ + i] * proj_w[(128 + i) * E_ + e];
        tab[1280 + t * E_ + e] = s;
    }
}

// ---------------------------------------------------------------------------
// Kernel 1: per (n,t) block. feat build -> cosine adjacency softmax -> adj@feat
// -> GCN (2 GEMMs) -> spatial MHSA over V + residual -> feat1 (global).
// ---------------------------------------------------------------------------
__global__ __launch_bounds__(128) void k_spatial(
    const float* __restrict__ xj, const float* __restrict__ xv,
    const float* __restrict__ tab,
    const float* __restrict__ w1, const float* __restrict__ b1,
    const float* __restrict__ w2, const float* __restrict__ b2,
    const float* __restrict__ wq, const float* __restrict__ bq,
    const float* __restrict__ wk, const float* __restrict__ bk,
    const float* __restrict__ wv, const float* __restrict__ bv,
    const float* __restrict__ wo, const float* __restrict__ bo,
    float* __restrict__ feat1) {
    int nt = blockIdx.x;
    int n = nt / T_;
    int t = nt % T_;
    int tid = threadIdx.x;

    __shared__ float feat[V_][E_];
    __shared__ float bufA[V_][E_];
    __shared__ float bufB[V_][E_];
    __shared__ float bufC[V_][E_];
    __shared__ float sc[H_][V_][16];
    __shared__ float adj[V_][16];
    __shared__ float xs[2][C_][V_];
    __shared__ float inv_nrm[V_];

    // stage x slices
    for (int i = tid; i < C_ * V_; i += 128) {
        int c = i / V_, v = i % V_;
        xs[0][c][v] = xj[((size_t)(n * C_ + c) * T_ + t) * V_ + v];
        xs[1][c][v] = xv[((size_t)(n * C_ + c) * T_ + t) * V_ + v];
    }
    __syncthreads();

    // feat = 6 FMAs + table adds
    for (int o = tid; o < V_ * E_; o += 128) {
        int v = o >> 6, e = o & 63;
        float s = tab[1280 + t * E_ + e] + tab[384 + v * E_ + e];
#pragma unroll
        for (int c = 0; c < C_; ++c) {
            s += xs[0][c][v] * tab[c * E_ + e];
            s += xs[1][c][v] * tab[192 + c * E_ + e];
        }
        feat[v][e] = s;
    }
    __syncthreads();

    // row inverse norms
    if (tid < V_) {
        float ss = 0.f;
        for (int e = 0; e < E_; ++e) { float f = feat[tid][e]; ss += f * f; }
        inv_nrm[tid] = 1.0f / fmaxf(sqrtf(ss), 1e-12f);
    }
    __syncthreads();

    // adjacency scores (cosine sim)
    for (int o = tid; o < V_ * V_; o += 128) {
        int q = o / V_, k = o % V_;
        float s = 0.f;
        for (int e = 0; e < E_; ++e) s += feat[q][e] * feat[k][e];
        adj[q][k] = s * inv_nrm[q] * inv_nrm[k];
    }
    __syncthreads();
    if (tid < V_) {
        float m = -1e30f;
        for (int k = 0; k < V_; ++k) m = fmaxf(m, adj[tid][k]);
        float sum = 0.f;
        for (int k = 0; k < V_; ++k) { float ex = expf(adj[tid][k] - m); adj[tid][k] = ex; sum += ex; }
        float inv = 1.0f / sum;
        for (int k = 0; k < V_; ++k) adj[tid][k] *= inv;
    }
    __syncthreads();

    // bufA = adj @ feat
    for (int o = tid; o < V_ * E_; o += 128) {
        int q = o >> 6, e = o & 63;
        float s = 0.f;
#pragma unroll
        for (int k = 0; k < V_; ++k) s += adj[q][k] * feat[k][e];
        bufA[q][e] = s;
    }
    __syncthreads();

    // bufB = relu(bufA @ W1 + b1)
    for (int o = tid; o < V_ * E_; o += 128) {
        int q = o >> 6, e = o & 63;
        float s = b1[e];
        for (int i = 0; i < E_; ++i) s += bufA[q][i] * w1[i * E_ + e];
        bufB[q][e] = fmaxf(s, 0.f);
    }
    __syncthreads();

    // feat = bufB @ W2 + b2   (post-GCN, also the MHSA residual)
    for (int o = tid; o < V_ * E_; o += 128) {
        int q = o >> 6, e = o & 63;
        float s = b2[e];
        for (int i = 0; i < E_; ++i) s += bufB[q][i] * w2[i * E_ + e];
        feat[q][e] = s;
    }
    __syncthreads();

    // q,k,v
    for (int o = tid; o < V_ * E_; o += 128) {
        int q = o >> 6, e = o & 63;
        float sq = bq[e], sk = bk[e], sv = bv[e];
        for (int i = 0; i < E_; ++i) {
            float f = feat[q][i];
            sq += f * wq[i * E_ + e];
            sk += f * wk[i * E_ + e];
            sv += f * wv[i * E_ + e];
        }
        bufA[q][e] = sq; bufB[q][e] = sk; bufC[q][e] = sv;
    }
    __syncthreads();

    // per-head scores
    for (int o = tid; o < H_ * V_ * V_; o += 128) {
        int h = o / (V_ * V_); int r = o % (V_ * V_); int q = r / V_, k = r % V_;
        float s = 0.f;
#pragma unroll
        for (int j = 0; j < D_; ++j) s += bufA[q][h * D_ + j] * bufB[k][h * D_ + j];
        sc[h][q][k] = s * 0.25f;  // 1/sqrt(16)
    }
    __syncthreads();
    if (tid < H_ * V_) {
        int h = tid / V_, q = tid % V_;
        float m = -1e30f;
        for (int k = 0; k < V_; ++k) m = fmaxf(m, sc[h][q][k]);
        float sum = 0.f;
        for (int k = 0; k < V_; ++k) { float ex = expf(sc[h][q][k] - m); sc[h][q][k] = ex; sum += ex; }
        float inv = 1.0f / sum;
        for (int k = 0; k < V_; ++k) sc[h][q][k] *= inv;
    }
    __syncthreads();

    // attn output -> bufB (k dead after scores)
    for (int o = tid; o < V_ * E_; o += 128) {
        int q = o >> 6, e = o & 63;
        int h = e / D_;
        float s = 0.f;
#pragma unroll
        for (int k = 0; k < V_; ++k) s += sc[h][q][k] * bufC[k][e];
        bufB[q][e] = s;
    }
    __syncthreads();

    // feat1 = feat + bufB @ Wo + bo
    for (int o = tid; o < V_ * E_; o += 128) {
        int q = o >> 6, e = o & 63;
        float s = bo[e];
        for (int i = 0; i < E_; ++i) s += bufB[q][i] * wo[i * E_ + e];
        feat1[(size_t)nt * (V_ * E_) + o] = feat[q][e] + s;
    }
}

// ---------------------------------------------------------------------------
// Kernel 2: per (n,v) block. Temporal MHSA over T + residual, then max over T.
// ---------------------------------------------------------------------------
__global__ __launch_bounds__(128) void k_temporal(
    const float* __restrict__ feat1,
    const float* __restrict__ wq, const float* __restrict__ bq,
    const float* __restrict__ wk, const float* __restrict__ bk,
    const float* __restrict__ wv, const float* __restrict__ bv,
    const float* __restrict__ wo, const float* __restrict__ bo,
    float* __restrict__ tmax) {
    int nv = blockIdx.x;
    int n = nv / V_;
    int v = nv % V_;
    int tid = threadIdx.x;

    __shared__ float ft[T_][E_];
    __shared__ float bufA[T_][E_];
    __shared__ float bufB[T_][E_];
    __shared__ float sc[H_][T_][32];

    for (int o = tid; o < T_ * E_; o += 128) {
        int t = o >> 6, e = o & 63;
        ft[t][e] = feat1[((size_t)(n * T_ + t) * V_ + v) * E_ + e];
    }
    __syncthreads();

    // q,k
    for (int o = tid; o < T_ * E_; o += 128) {
        int t = o >> 6, e = o & 63;
        float sq = bq[e], sk = bk[e];
        for (int i = 0; i < E_; ++i) {
            float f = ft[t][i];
            sq += f * wq[i * E_ + e];
            sk += f * wk[i * E_ + e];
        }
        bufA[t][e] = sq; bufB[t][e] = sk;
    }
    __syncthreads();

    // all-head scores
    for (int o = tid; o < H_ * T_ * T_; o += 128) {
        int h = o / (T_ * T_); int r = o % (T_ * T_); int q = r / T_, k = r % T_;
        float s = 0.f;
#pragma unroll
        for (int j = 0; j < D_; ++j) s += bufA[q][h * D_ + j] * bufB[k][h * D_ + j];
        sc[h][q][k] = s * 0.25f;
    }
    __syncthreads();
    if (tid < H_ * T_) {
        int h = tid / T_, q = tid % T_;
        float m = -1e30f;
        for (int k = 0; k < T_; ++k) m = fmaxf(m, sc[h][q][k]);
        float sum = 0.f;
        for (int k = 0; k < T_; ++k) { float ex = expf(sc[h][q][k] - m); sc[h][q][k] = ex; sum += ex; }
        float inv = 1.0f / sum;
        for (int k = 0; k < T_; ++k) sc[h][q][k] *= inv;
    }
    __syncthreads();

    // v -> bufA (q dead)
    for (int o = tid; o < T_ * E_; o += 128) {
        int t = o >> 6, e = o & 63;
        float sv = bv[e];
        for (int i = 0; i < E_; ++i) sv += ft[t][i] * wv[i * E_ + e];
        bufA[t][e] = sv;
    }
    __syncthreads();

    // attn output -> bufB (k dead)
    for (int o = tid; o < T_ * E_; o += 128) {
        int q = o >> 6, e = o & 63;
        int h = e / D_;
        float s = 0.f;
#pragma unroll
        for (int k = 0; k < T_; ++k) s += sc[h][q][k] * bufA[k][e];
        bufB[q][e] = s;
    }
    __syncthreads();

    // ft += bufB @ Wo + bo   (elementwise residual: in-place safe)
    for (int o = tid; o < T_ * E_; o += 128) {
        int q = o >> 6, e = o & 63;
        float s = bo[e];
        for (int i = 0; i < E_; ++i) s += bufB[q][i] * wo[i * E_ + e];
        ft[q][e] += s;
    }
    __syncthreads();

    if (tid < E_) {
        float m = -1e30f;
        for (int t = 0; t < T_; ++t) m = fmaxf(m, ft[t][tid]);
        tmax[(size_t)nv * E_ + tid] = m;
    }
}

// ---------------------------------------------------------------------------
// Kernel 3: per n — max over V, then FC to 7 classes.
// ---------------------------------------------------------------------------
__global__ void k_pool_fc(const float* __restrict__ tmax,
                          const float* __restrict__ fc_w, const float* __restrict__ fc_b,
                          float* __restrict__ out) {
    int n = blockIdx.x;
    int tid = threadIdx.x;  // 64
    __shared__ float pooled[E_];
    float m = -1e30f;
    for (int v = 0; v < V_; ++v) m = fmaxf(m, tmax[((size_t)n * V_ + v) * E_ + tid]);
    pooled[tid] = m;
    __syncthreads();
    if (tid < NC_) {
        float s = fc_b[tid];
        for (int e = 0; e < E_; ++e) s += pooled[e] * fc_w[e * NC_ + tid];
        out[n * NC_ + tid] = s;
    }
}

extern "C" void kernel_launch(void* const* d_in, const int* in_sizes, int n_in,
                              void* d_out, int out_size, void* d_ws, size_t ws_size,
                              hipStream_t stream) {
    const float* xj        = (const float*)d_in[0];
    const float* xv        = (const float*)d_in[1];
    const float* je_w      = (const float*)d_in[2];
    const float* je_b      = (const float*)d_in[3];
    const float* ve_w      = (const float*)d_in[4];
    const float* ve_b      = (const float*)d_in[5];
    const float* joint_emb = (const float*)d_in[6];
    const float* frame_emb = (const float*)d_in[7];
    const float* proj_w    = (const float*)d_in[8];
    const float* proj_b    = (const float*)d_in[9];
    const float* gcn_w1    = (const float*)d_in[10];
    const float* gcn_b1    = (const float*)d_in[11];
    const float* gcn_w2    = (const float*)d_in[12];
    const float* gcn_b2    = (const float*)d_in[13];
    const float* sa_wq     = (const float*)d_in[14];
    const float* sa_bq     = (const float*)d_in[15];
    const float* sa_wk     = (const float*)d_in[16];
    const float* sa_bk     = (const float*)d_in[17];
    const float* sa_wv     = (const float*)d_in[18];
    const float* sa_bv     = (const float*)d_in[19];
    const float* sa_wo     = (const float*)d_in[20];
    const float* sa_bo     = (const float*)d_in[21];
    const float* ta_wq     = (const float*)d_in[22];
    const float* ta_bq     = (const float*)d_in[23];
    const float* ta_wk     = (const float*)d_in[24];
    const float* ta_bk     = (const float*)d_in[25];
    const float* ta_wv     = (const float*)d_in[26];
    const float* ta_bv     = (const float*)d_in[27];
    const float* ta_wo     = (const float*)d_in[28];
    const float* ta_bo     = (const float*)d_in[29];
    const float* fc_w      = (const float*)d_in[30];
    const float* fc_b      = (const float*)d_in[31];
    float* out = (float*)d_out;

    int N = in_sizes[0] / (C_ * T_ * V_);

    // ws layout (floats): tab[3200] | tmax[N*V*E] | feat1[N*T*V*E]
    float* ws    = (float*)d_ws;
    float* tab   = ws;
    float* tmax  = ws + 3200;
    float* feat1 = tmax + (size_t)N * V_ * E_;

    k_setup<<<1, 64, 0, stream>>>(je_w, je_b, ve_w, ve_b, joint_emb, frame_emb,
                                  proj_w, proj_b, tab);
    k_spatial<<<N * T_, 128, 0, stream>>>(xj, xv, tab,
                                          gcn_w1, gcn_b1, gcn_w2, gcn_b2,
                                          sa_wq, sa_bq, sa_wk, sa_bk,
                                          sa_wv, sa_bv, sa_wo, sa_bo, feat1);
    k_temporal<<<N * V_, 128, 0, stream>>>(feat1,
                                           ta_wq, ta_bq, ta_wk, ta_bk,
                                           ta_wv, ta_bv, ta_wo, ta_bo, tmax);
    k_pool_fc<<<N, 64, 0, stream>>>(tmax, fc_w, fc_b, out);
}

// Round 2
// 2299.575 us; speedup vs baseline: 1.1740x; 1.1740x over previous
//
#include <hip/hip_runtime.h>
#include <math.h>

#define C_ 3
#define T_ 30
#define V_ 14
#define E_ 64
#define H_ 4
#define D_ 16
#define NC_ 7

// Padded LDS strides (conflict-free column walks: stride%32 coprime-ish)
#define EP_ 65   // row stride for [*,E] tiles: bank = (row + e) % 32
#define SCT_ 31  // sc row stride, temporal (k<30)
#define SCV_ 15  // sc/adj row stride, spatial (k<14)

// ---------------------------------------------------------------------------
// Setup: collapse the linear front-end into small tables in ws:
//   tab[0..191]     A_j[c][e]   = je_w @ P0
//   tab[192..383]   A_v[c][e]   = ve_w @ P0
//   tab[384..1279]  jproj[v][e] = joint_emb @ P1
//   tab[1280..3199] fprojb[t][e]= frame_emb @ P2 + proj_b + (je_b+ve_b) @ P0
// ---------------------------------------------------------------------------
__global__ void k_setup(const float* __restrict__ je_w, const float* __restrict__ je_b,
                        const float* __restrict__ ve_w, const float* __restrict__ ve_b,
                        const float* __restrict__ joint_emb, const float* __restrict__ frame_emb,
                        const float* __restrict__ proj_w, const float* __restrict__ proj_b,
                        float* __restrict__ tab) {
    int e = threadIdx.x;  // 64 threads
    for (int c = 0; c < C_; ++c) {
        float aj = 0.f, av = 0.f;
        for (int i = 0; i < E_; ++i) {
            float p0 = proj_w[i * E_ + e];
            aj += je_w[c * E_ + i] * p0;
            av += ve_w[c * E_ + i] * p0;
        }
        tab[c * E_ + e] = aj;
        tab[192 + c * E_ + e] = av;
    }
    for (int v = 0; v < V_; ++v) {
        float s = 0.f;
        for (int i = 0; i < E_; ++i) s += joint_emb[v * E_ + i] * proj_w[(64 + i) * E_ + e];
        tab[384 + v * E_ + e] = s;
    }
    float bias = proj_b[e];
    for (int i = 0; i < E_; ++i) bias += (je_b[i] + ve_b[i]) * proj_w[i * E_ + e];
    for (int t = 0; t < T_; ++t) {
        float s = bias;
        for (int i = 0; i < E_; ++i) s += frame_emb[t * E_ + i] * proj_w[(128 + i) * E_ + e];
        tab[1280 + t * E_ + e] = s;
    }
}

// ---------------------------------------------------------------------------
// Kernel 1: per (n,t) block. feat build -> cosine adjacency softmax -> adj@feat
// -> GCN (2 GEMMs) -> spatial MHSA over V + residual -> feat1 (global).
// ---------------------------------------------------------------------------
__global__ __launch_bounds__(128) void k_spatial(
    const float* __restrict__ xj, const float* __restrict__ xv,
    const float* __restrict__ tab,
    const float* __restrict__ w1, const float* __restrict__ b1,
    const float* __restrict__ w2, const float* __restrict__ b2,
    const float* __restrict__ wq, const float* __restrict__ bq,
    const float* __restrict__ wk, const float* __restrict__ bk,
    const float* __restrict__ wv, const float* __restrict__ bv,
    const float* __restrict__ wo, const float* __restrict__ bo,
    float* __restrict__ feat1) {
    int nt = blockIdx.x;
    int n = nt / T_;
    int t = nt % T_;
    int tid = threadIdx.x;

    __shared__ float feat[V_][EP_];
    __shared__ float bufA[V_][EP_];
    __shared__ float bufB[V_][EP_];
    __shared__ float bufC[V_][EP_];
    __shared__ float sc[H_][V_][SCV_];
    __shared__ float adj[V_][SCV_];
    __shared__ float xs[2][C_][V_];
    __shared__ float inv_nrm[V_];

    // stage x slices
    for (int i = tid; i < C_ * V_; i += 128) {
        int c = i / V_, v = i % V_;
        xs[0][c][v] = xj[((size_t)(n * C_ + c) * T_ + t) * V_ + v];
        xs[1][c][v] = xv[((size_t)(n * C_ + c) * T_ + t) * V_ + v];
    }
    __syncthreads();

    // feat = 6 FMAs + table adds
    for (int o = tid; o < V_ * E_; o += 128) {
        int v = o >> 6, e = o & 63;
        float s = tab[1280 + t * E_ + e] + tab[384 + v * E_ + e];
#pragma unroll
        for (int c = 0; c < C_; ++c) {
            s += xs[0][c][v] * tab[c * E_ + e];
            s += xs[1][c][v] * tab[192 + c * E_ + e];
        }
        feat[v][e] = s;
    }
    __syncthreads();

    // row inverse norms
    if (tid < V_) {
        float ss = 0.f;
        for (int e = 0; e < E_; ++e) { float f = feat[tid][e]; ss += f * f; }
        inv_nrm[tid] = 1.0f / fmaxf(sqrtf(ss), 1e-12f);
    }
    __syncthreads();

    // adjacency scores (cosine sim)
    for (int o = tid; o < V_ * V_; o += 128) {
        int q = o / V_, k = o % V_;
        float s = 0.f;
        for (int e = 0; e < E_; ++e) s += feat[q][e] * feat[k][e];
        adj[q][k] = s * inv_nrm[q] * inv_nrm[k];
    }
    __syncthreads();
    if (tid < V_) {
        float m = -1e30f;
        for (int k = 0; k < V_; ++k) m = fmaxf(m, adj[tid][k]);
        float sum = 0.f;
        for (int k = 0; k < V_; ++k) { float ex = expf(adj[tid][k] - m); adj[tid][k] = ex; sum += ex; }
        float inv = 1.0f / sum;
        for (int k = 0; k < V_; ++k) adj[tid][k] *= inv;
    }
    __syncthreads();

    // bufA = adj @ feat
    for (int o = tid; o < V_ * E_; o += 128) {
        int q = o >> 6, e = o & 63;
        float s = 0.f;
#pragma unroll
        for (int k = 0; k < V_; ++k) s += adj[q][k] * feat[k][e];
        bufA[q][e] = s;
    }
    __syncthreads();

    // bufB = relu(bufA @ W1 + b1)
    for (int o = tid; o < V_ * E_; o += 128) {
        int q = o >> 6, e = o & 63;
        float s = b1[e];
        for (int i = 0; i < E_; ++i) s += bufA[q][i] * w1[i * E_ + e];
        bufB[q][e] = fmaxf(s, 0.f);
    }
    __syncthreads();

    // feat = bufB @ W2 + b2   (post-GCN, also the MHSA residual)
    for (int o = tid; o < V_ * E_; o += 128) {
        int q = o >> 6, e = o & 63;
        float s = b2[e];
        for (int i = 0; i < E_; ++i) s += bufB[q][i] * w2[i * E_ + e];
        feat[q][e] = s;
    }
    __syncthreads();

    // q,k,v
    for (int o = tid; o < V_ * E_; o += 128) {
        int q = o >> 6, e = o & 63;
        float sq = bq[e], sk = bk[e], sv = bv[e];
        for (int i = 0; i < E_; ++i) {
            float f = feat[q][i];
            sq += f * wq[i * E_ + e];
            sk += f * wk[i * E_ + e];
            sv += f * wv[i * E_ + e];
        }
        bufA[q][e] = sq; bufB[q][e] = sk; bufC[q][e] = sv;
    }
    __syncthreads();

    // per-head scores
    for (int o = tid; o < H_ * V_ * V_; o += 128) {
        int h = o / (V_ * V_); int r = o % (V_ * V_); int q = r / V_, k = r % V_;
        float s = 0.f;
#pragma unroll
        for (int j = 0; j < D_; ++j) s += bufA[q][h * D_ + j] * bufB[k][h * D_ + j];
        sc[h][q][k] = s * 0.25f;  // 1/sqrt(16)
    }
    __syncthreads();
    if (tid < H_ * V_) {
        int h = tid / V_, q = tid % V_;
        float m = -1e30f;
        for (int k = 0; k < V_; ++k) m = fmaxf(m, sc[h][q][k]);
        float sum = 0.f;
        for (int k = 0; k < V_; ++k) { float ex = expf(sc[h][q][k] - m); sc[h][q][k] = ex; sum += ex; }
        float inv = 1.0f / sum;
        for (int k = 0; k < V_; ++k) sc[h][q][k] *= inv;
    }
    __syncthreads();

    // attn output -> bufB (k dead after scores)
    for (int o = tid; o < V_ * E_; o += 128) {
        int q = o >> 6, e = o & 63;
        int h = e / D_;
        float s = 0.f;
#pragma unroll
        for (int k = 0; k < V_; ++k) s += sc[h][q][k] * bufC[k][e];
        bufB[q][e] = s;
    }
    __syncthreads();

    // feat1 = feat + bufB @ Wo + bo
    for (int o = tid; o < V_ * E_; o += 128) {
        int q = o >> 6, e = o & 63;
        float s = bo[e];
        for (int i = 0; i < E_; ++i) s += bufB[q][i] * wo[i * E_ + e];
        feat1[(size_t)nt * (V_ * E_) + o] = feat[q][e] + s;
    }
}

// ---------------------------------------------------------------------------
// Kernel 2: per (n,v) block. Temporal MHSA over T + residual, then max over T.
// 256 threads: 4 waves/block, ~4 blocks/CU -> 16 waves/CU.
// ---------------------------------------------------------------------------
__global__ __launch_bounds__(256) void k_temporal(
    const float* __restrict__ feat1,
    const float* __restrict__ wq, const float* __restrict__ bq,
    const float* __restrict__ wk, const float* __restrict__ bk,
    const float* __restrict__ wv, const float* __restrict__ bv,
    const float* __restrict__ wo, const float* __restrict__ bo,
    float* __restrict__ tmax) {
    int nv = blockIdx.x;
    int n = nv / V_;
    int v = nv % V_;
    int tid = threadIdx.x;

    __shared__ float ft[T_][EP_];
    __shared__ float bufA[T_][EP_];
    __shared__ float bufB[T_][EP_];
    __shared__ float sc[H_][T_][SCT_];

    for (int o = tid; o < T_ * E_; o += 256) {
        int t = o >> 6, e = o & 63;
        ft[t][e] = feat1[((size_t)(n * T_ + t) * V_ + v) * E_ + e];
    }
    __syncthreads();

    // q,k
    for (int o = tid; o < T_ * E_; o += 256) {
        int t = o >> 6, e = o & 63;
        float sq = bq[e], sk = bk[e];
        for (int i = 0; i < E_; ++i) {
            float f = ft[t][i];
            sq += f * wq[i * E_ + e];
            sk += f * wk[i * E_ + e];
        }
        bufA[t][e] = sq; bufB[t][e] = sk;
    }
    __syncthreads();

    // all-head scores
    for (int o = tid; o < H_ * T_ * T_; o += 256) {
        int h = o / (T_ * T_); int r = o % (T_ * T_); int q = r / T_, k = r % T_;
        float s = 0.f;
#pragma unroll
        for (int j = 0; j < D_; ++j) s += bufA[q][h * D_ + j] * bufB[k][h * D_ + j];
        sc[h][q][k] = s * 0.25f;
    }
    __syncthreads();
    if (tid < H_ * T_) {
        int h = tid / T_, q = tid % T_;
        float m = -1e30f;
        for (int k = 0; k < T_; ++k) m = fmaxf(m, sc[h][q][k]);
        float sum = 0.f;
        for (int k = 0; k < T_; ++k) { float ex = expf(sc[h][q][k] - m); sc[h][q][k] = ex; sum += ex; }
        float inv = 1.0f / sum;
        for (int k = 0; k < T_; ++k) sc[h][q][k] *= inv;
    }
    __syncthreads();

    // v -> bufA (q dead)
    for (int o = tid; o < T_ * E_; o += 256) {
        int t = o >> 6, e = o & 63;
        float sv = bv[e];
        for (int i = 0; i < E_; ++i) sv += ft[t][i] * wv[i * E_ + e];
        bufA[t][e] = sv;
    }
    __syncthreads();

    // attn output -> bufB (k dead)
    for (int o = tid; o < T_ * E_; o += 256) {
        int q = o >> 6, e = o & 63;
        int h = e / D_;
        float s = 0.f;
#pragma unroll
        for (int k = 0; k < T_; ++k) s += sc[h][q][k] * bufA[k][e];
        bufB[q][e] = s;
    }
    __syncthreads();

    // ft += bufB @ Wo + bo   (elementwise residual: in-place safe)
    for (int o = tid; o < T_ * E_; o += 256) {
        int q = o >> 6, e = o & 63;
        float s = bo[e];
        for (int i = 0; i < E_; ++i) s += bufB[q][i] * wo[i * E_ + e];
        ft[q][e] += s;
    }
    __syncthreads();

    if (tid < E_) {
        float m = -1e30f;
        for (int t = 0; t < T_; ++t) m = fmaxf(m, ft[t][tid]);
        tmax[(size_t)nv * E_ + tid] = m;
    }
}

// ---------------------------------------------------------------------------
// Kernel 3: per n — max over V, then FC to 7 classes.
// ---------------------------------------------------------------------------
__global__ void k_pool_fc(const float* __restrict__ tmax,
                          const float* __restrict__ fc_w, const float* __restrict__ fc_b,
                          float* __restrict__ out) {
    int n = blockIdx.x;
    int tid = threadIdx.x;  // 64
    __shared__ float pooled[E_];
    float m = -1e30f;
    for (int v = 0; v < V_; ++v) m = fmaxf(m, tmax[((size_t)n * V_ + v) * E_ + tid]);
    pooled[tid] = m;
    __syncthreads();
    if (tid < NC_) {
        float s = fc_b[tid];
        for (int e = 0; e < E_; ++e) s += pooled[e] * fc_w[e * NC_ + tid];
        out[n * NC_ + tid] = s;
    }
}

extern "C" void kernel_launch(void* const* d_in, const int* in_sizes, int n_in,
                              void* d_out, int out_size, void* d_ws, size_t ws_size,
                              hipStream_t stream) {
    const float* xj        = (const float*)d_in[0];
    const float* xv        = (const float*)d_in[1];
    const float* je_w      = (const float*)d_in[2];
    const float* je_b      = (const float*)d_in[3];
    const float* ve_w      = (const float*)d_in[4];
    const float* ve_b      = (const float*)d_in[5];
    const float* joint_emb = (const float*)d_in[6];
    const float* frame_emb = (const float*)d_in[7];
    const float* proj_w    = (const float*)d_in[8];
    const float* proj_b    = (const float*)d_in[9];
    const float* gcn_w1    = (const float*)d_in[10];
    const float* gcn_b1    = (const float*)d_in[11];
    const float* gcn_w2    = (const float*)d_in[12];
    const float* gcn_b2    = (const float*)d_in[13];
    const float* sa_wq     = (const float*)d_in[14];
    const float* sa_bq     = (const float*)d_in[15];
    const float* sa_wk     = (const float*)d_in[16];
    const float* sa_bk     = (const float*)d_in[17];
    const float* sa_wv     = (const float*)d_in[18];
    const float* sa_bv     = (const float*)d_in[19];
    const float* sa_wo     = (const float*)d_in[20];
    const float* sa_bo     = (const float*)d_in[21];
    const float* ta_wq     = (const float*)d_in[22];
    const float* ta_bq     = (const float*)d_in[23];
    const float* ta_wk     = (const float*)d_in[24];
    const float* ta_bk     = (const float*)d_in[25];
    const float* ta_wv     = (const float*)d_in[26];
    const float* ta_bv     = (const float*)d_in[27];
    const float* ta_wo     = (const float*)d_in[28];
    const float* ta_bo     = (const float*)d_in[29];
    const float* fc_w      = (const float*)d_in[30];
    const float* fc_b      = (const float*)d_in[31];
    float* out = (float*)d_out;

    int N = in_sizes[0] / (C_ * T_ * V_);

    // ws layout (floats): tab[3200] | tmax[N*V*E] | feat1[N*T*V*E]
    float* ws    = (float*)d_ws;
    float* tab   = ws;
    float* tmax  = ws + 3200;
    float* feat1 = tmax + (size_t)N * V_ * E_;

    k_setup<<<1, 64, 0, stream>>>(je_w, je_b, ve_w, ve_b, joint_emb, frame_emb,
                                  proj_w, proj_b, tab);
    k_spatial<<<N * T_, 128, 0, stream>>>(xj, xv, tab,
                                          gcn_w1, gcn_b1, gcn_w2, gcn_b2,
                                          sa_wq, sa_bq, sa_wk, sa_bk,
                                          sa_wv, sa_bv, sa_wo, sa_bo, feat1);
    k_temporal<<<N * V_, 256, 0, stream>>>(feat1,
                                           ta_wq, ta_bq, ta_wk, ta_bk,
                                           ta_wv, ta_bv, ta_wo, ta_bo, tmax);
    k_pool_fc<<<N, 64, 0, stream>>>(tmax, fc_w, fc_b, out);
}

// Round 3
// 2270.437 us; speedup vs baseline: 1.1891x; 1.0128x over previous
//
#include <hip/hip_runtime.h>
#include <math.h>

#define C_ 3
#define T_ 30
#define V_ 14
#define E_ 64
#define H_ 4
#define D_ 16
#define NC_ 7

#define EP_ 68   // padded row stride for [*,E] LDS tiles: 16B-aligned rows, banks spread
#define SCT_ 31  // sc row stride, temporal
#define SCV_ 15  // sc/adj row stride, spatial

__device__ __forceinline__ float4 f4_load(const float* p) {
    return *reinterpret_cast<const float4*>(p);
}
__device__ __forceinline__ float4 f4_zero() { return make_float4(0.f, 0.f, 0.f, 0.f); }
__device__ __forceinline__ float4 f4_add(float4 a, float4 b) {
    return make_float4(a.x + b.x, a.y + b.y, a.z + b.z, a.w + b.w);
}
__device__ __forceinline__ float4 f4_fma(float a, float4 b, float4 c) {
    c.x = fmaf(a, b.x, c.x); c.y = fmaf(a, b.y, c.y);
    c.z = fmaf(a, b.z, c.z); c.w = fmaf(a, b.w, c.w); return c;
}
__device__ __forceinline__ float f4_dot(float4 a, float4 b) {
    return a.x * b.x + a.y * b.y + a.z * b.z + a.w * b.w;
}
__device__ __forceinline__ float4 f4_relu(float4 a) {
    return make_float4(fmaxf(a.x, 0.f), fmaxf(a.y, 0.f), fmaxf(a.z, 0.f), fmaxf(a.w, 0.f));
}

// ---------------------------------------------------------------------------
// Setup: collapse the linear front-end into small tables in ws.
// ---------------------------------------------------------------------------
__global__ void k_setup(const float* __restrict__ je_w, const float* __restrict__ je_b,
                        const float* __restrict__ ve_w, const float* __restrict__ ve_b,
                        const float* __restrict__ joint_emb, const float* __restrict__ frame_emb,
                        const float* __restrict__ proj_w, const float* __restrict__ proj_b,
                        float* __restrict__ tab) {
    int e = threadIdx.x;  // 64 threads
    for (int c = 0; c < C_; ++c) {
        float aj = 0.f, av = 0.f;
        for (int i = 0; i < E_; ++i) {
            float p0 = proj_w[i * E_ + e];
            aj += je_w[c * E_ + i] * p0;
            av += ve_w[c * E_ + i] * p0;
        }
        tab[c * E_ + e] = aj;
        tab[192 + c * E_ + e] = av;
    }
    for (int v = 0; v < V_; ++v) {
        float s = 0.f;
        for (int i = 0; i < E_; ++i) s += joint_emb[v * E_ + i] * proj_w[(64 + i) * E_ + e];
        tab[384 + v * E_ + e] = s;
    }
    float bias = proj_b[e];
    for (int i = 0; i < E_; ++i) bias += (je_b[i] + ve_b[i]) * proj_w[i * E_ + e];
    for (int t = 0; t < T_; ++t) {
        float s = bias;
        for (int i = 0; i < E_; ++i) s += frame_emb[t * E_ + i] * proj_w[(128 + i) * E_ + e];
        tab[1280 + t * E_ + e] = s;
    }
}

// ---------------------------------------------------------------------------
// Kernel 1: per (n,t). Register-blocked float4 GEMM phases: each thread owns
// rows {r8, r8+8} x 4 consecutive e. One float4 weight load feeds 8 FMAs.
// ---------------------------------------------------------------------------
__global__ __launch_bounds__(128) void k_spatial(
    const float* __restrict__ xj, const float* __restrict__ xv,
    const float* __restrict__ tab,
    const float* __restrict__ w1, const float* __restrict__ b1,
    const float* __restrict__ w2, const float* __restrict__ b2,
    const float* __restrict__ wq, const float* __restrict__ bq,
    const float* __restrict__ wk, const float* __restrict__ bk,
    const float* __restrict__ wv, const float* __restrict__ bv,
    const float* __restrict__ wo, const float* __restrict__ bo,
    float* __restrict__ feat1) {
    int nt = blockIdx.x;
    int n = nt / T_;
    int t = nt % T_;
    int tid = threadIdx.x;
    int l16 = tid & 15;
    int e4 = l16 << 2;
    int r8 = tid >> 4;          // 0..7
    int q0 = r8, q1 = r8 + 8;
    int q1c = (q1 < V_) ? q1 : 0;   // clamped for branchless compute

    __shared__ __align__(16) float feat[V_][EP_];
    __shared__ __align__(16) float bufA[V_][EP_];
    __shared__ __align__(16) float bufB[V_][EP_];
    __shared__ float sc[H_][V_][SCV_];
    __shared__ float adj[V_][SCV_];
    __shared__ float xs[2][C_][V_];
    __shared__ float inv_nrm[V_];

    // stage x slices (84 threads)
    if (tid < 2 * C_ * V_) {
        int s = tid / (C_ * V_);
        int rem = tid % (C_ * V_);
        int c = rem / V_, v = rem % V_;
        const float* src = s ? xv : xj;
        xs[s][c][v] = src[((size_t)(n * C_ + c) * T_ + t) * V_ + v];
    }
    __syncthreads();

    // feat build
    {
        float4 F = f4_load(tab + 1280 + t * E_ + e4);
        float4 AJ[C_], AV[C_];
#pragma unroll
        for (int c = 0; c < C_; ++c) {
            AJ[c] = f4_load(tab + c * E_ + e4);
            AV[c] = f4_load(tab + 192 + c * E_ + e4);
        }
        for (int q = r8; q < V_; q += 8) {
            float4 s = f4_add(F, f4_load(tab + 384 + q * E_ + e4));
#pragma unroll
            for (int c = 0; c < C_; ++c) {
                s = f4_fma(xs[0][c][q], AJ[c], s);
                s = f4_fma(xs[1][c][q], AV[c], s);
            }
            *(float4*)&feat[q][e4] = s;
        }
    }
    __syncthreads();

    // row inverse norms
    if (tid < V_) {
        float ss = 0.f;
#pragma unroll
        for (int j = 0; j < 16; ++j) { float4 f = f4_load(&feat[tid][4 * j]); ss += f4_dot(f, f); }
        inv_nrm[tid] = 1.0f / fmaxf(sqrtf(ss), 1e-12f);
    }
    __syncthreads();

    // adjacency scores (cosine sim)
    for (int o = tid; o < V_ * V_; o += 128) {
        int q = o / V_, k = o % V_;
        float s = 0.f;
#pragma unroll
        for (int j = 0; j < 16; ++j) s += f4_dot(f4_load(&feat[q][4 * j]), f4_load(&feat[k][4 * j]));
        adj[q][k] = s * inv_nrm[q] * inv_nrm[k];
    }
    __syncthreads();
    if (tid < V_) {
        float m = -1e30f;
        for (int k = 0; k < V_; ++k) m = fmaxf(m, adj[tid][k]);
        float sum = 0.f;
        for (int k = 0; k < V_; ++k) { float ex = expf(adj[tid][k] - m); adj[tid][k] = ex; sum += ex; }
        float inv = 1.0f / sum;
        for (int k = 0; k < V_; ++k) adj[tid][k] *= inv;
    }
    __syncthreads();

    // bufA = adj @ feat
    for (int q = r8; q < V_; q += 8) {
        float4 acc = f4_zero();
#pragma unroll
        for (int k = 0; k < V_; ++k) acc = f4_fma(adj[q][k], f4_load(&feat[k][e4]), acc);
        *(float4*)&bufA[q][e4] = acc;
    }
    __syncthreads();

    // bufB = relu(bufA @ W1 + b1)
    {
        float4 acc0 = f4_load(b1 + e4), acc1 = acc0;
        for (int i = 0; i < E_; ++i) {
            float4 w4 = f4_load(w1 + i * E_ + e4);
            acc0 = f4_fma(bufA[q0][i], w4, acc0);
            acc1 = f4_fma(bufA[q1c][i], w4, acc1);
        }
        *(float4*)&bufB[q0][e4] = f4_relu(acc0);
        if (q1 < V_) *(float4*)&bufB[q1][e4] = f4_relu(acc1);
    }
    __syncthreads();

    // feat = bufB @ W2 + b2  (post-GCN = residual base)
    {
        float4 acc0 = f4_load(b2 + e4), acc1 = acc0;
        for (int i = 0; i < E_; ++i) {
            float4 w4 = f4_load(w2 + i * E_ + e4);
            acc0 = f4_fma(bufB[q0][i], w4, acc0);
            acc1 = f4_fma(bufB[q1c][i], w4, acc1);
        }
        *(float4*)&feat[q0][e4] = acc0;
        if (q1 < V_) *(float4*)&feat[q1][e4] = acc1;
    }
    __syncthreads();

    // q -> bufA, k -> bufB
    {
        float4 aq0 = f4_load(bq + e4), aq1 = aq0;
        float4 ak0 = f4_load(bk + e4), ak1 = ak0;
        for (int i = 0; i < E_; ++i) {
            float f0 = feat[q0][i], f1 = feat[q1c][i];
            float4 wq4 = f4_load(wq + i * E_ + e4);
            float4 wk4 = f4_load(wk + i * E_ + e4);
            aq0 = f4_fma(f0, wq4, aq0); aq1 = f4_fma(f1, wq4, aq1);
            ak0 = f4_fma(f0, wk4, ak0); ak1 = f4_fma(f1, wk4, ak1);
        }
        *(float4*)&bufA[q0][e4] = aq0; *(float4*)&bufB[q0][e4] = ak0;
        if (q1 < V_) { *(float4*)&bufA[q1][e4] = aq1; *(float4*)&bufB[q1][e4] = ak1; }
    }
    __syncthreads();

    // per-head scores
    for (int o = tid; o < H_ * V_ * V_; o += 128) {
        int h = o / (V_ * V_); int r = o % (V_ * V_); int q = r / V_, k = r % V_;
        float s = 0.f;
#pragma unroll
        for (int j = 0; j < 4; ++j)
            s += f4_dot(f4_load(&bufA[q][h * 16 + 4 * j]), f4_load(&bufB[k][h * 16 + 4 * j]));
        sc[h][q][k] = s * 0.25f;  // 1/sqrt(16)
    }
    __syncthreads();
    if (tid < H_ * V_) {
        int h = tid / V_, q = tid % V_;
        float m = -1e30f;
        for (int k = 0; k < V_; ++k) m = fmaxf(m, sc[h][q][k]);
        float sum = 0.f;
        for (int k = 0; k < V_; ++k) { float ex = expf(sc[h][q][k] - m); sc[h][q][k] = ex; sum += ex; }
        float inv = 1.0f / sum;
        for (int k = 0; k < V_; ++k) sc[h][q][k] *= inv;
    }
    __syncthreads();

    // v -> bufA (q dead after scores)
    {
        float4 av0 = f4_load(bv + e4), av1 = av0;
        for (int i = 0; i < E_; ++i) {
            float4 wv4 = f4_load(wv + i * E_ + e4);
            av0 = f4_fma(feat[q0][i], wv4, av0);
            av1 = f4_fma(feat[q1c][i], wv4, av1);
        }
        *(float4*)&bufA[q0][e4] = av0;
        if (q1 < V_) *(float4*)&bufA[q1][e4] = av1;
    }
    __syncthreads();

    // attn output -> bufB (k dead)
    {
        int h = l16 >> 2;
        for (int q = r8; q < V_; q += 8) {
            float4 acc = f4_zero();
#pragma unroll
            for (int k = 0; k < V_; ++k) acc = f4_fma(sc[h][q][k], f4_load(&bufA[k][e4]), acc);
            *(float4*)&bufB[q][e4] = acc;
        }
    }
    __syncthreads();

    // feat1 = feat + bufB @ Wo + bo
    {
        float4 acc0 = f4_load(bo + e4), acc1 = acc0;
        for (int i = 0; i < E_; ++i) {
            float4 w4 = f4_load(wo + i * E_ + e4);
            acc0 = f4_fma(bufB[q0][i], w4, acc0);
            acc1 = f4_fma(bufB[q1c][i], w4, acc1);
        }
        acc0 = f4_add(acc0, f4_load(&feat[q0][e4]));
        *(float4*)(feat1 + (size_t)nt * (V_ * E_) + q0 * E_ + e4) = acc0;
        if (q1 < V_) {
            acc1 = f4_add(acc1, f4_load(&feat[q1][e4]));
            *(float4*)(feat1 + (size_t)nt * (V_ * E_) + q1 * E_ + e4) = acc1;
        }
    }
}

// ---------------------------------------------------------------------------
// Kernel 2: per (n,v). Temporal MHSA over T + residual, then max over T.
// 256 threads: rows {r16, r16+16} x float4 e-chunk per thread.
// ---------------------------------------------------------------------------
__global__ __launch_bounds__(256) void k_temporal(
    const float* __restrict__ feat1,
    const float* __restrict__ wq, const float* __restrict__ bq,
    const float* __restrict__ wk, const float* __restrict__ bk,
    const float* __restrict__ wv, const float* __restrict__ bv,
    const float* __restrict__ wo, const float* __restrict__ bo,
    float* __restrict__ tmax) {
    int nv = blockIdx.x;
    int n = nv / V_;
    int v = nv % V_;
    int tid = threadIdx.x;
    int l16 = tid & 15;
    int e4 = l16 << 2;
    int r16 = tid >> 4;         // 0..15
    int t0 = r16, t1 = r16 + 16;
    int t1c = (t1 < T_) ? t1 : 0;

    __shared__ __align__(16) float ft[T_][EP_];
    __shared__ __align__(16) float bufA[T_][EP_];
    __shared__ __align__(16) float bufB[T_][EP_];
    __shared__ float sc[H_][T_][SCT_];

    for (int o = tid; o < T_ * 16; o += 256) {
        int tt = o >> 4, l = o & 15;
        *(float4*)&ft[tt][4 * l] =
            f4_load(feat1 + (((size_t)n * T_ + tt) * V_ + v) * E_ + 4 * l);
    }
    __syncthreads();

    // q -> bufA, k -> bufB
    {
        float4 aq0 = f4_load(bq + e4), aq1 = aq0;
        float4 ak0 = f4_load(bk + e4), ak1 = ak0;
        for (int i = 0; i < E_; ++i) {
            float f0 = ft[t0][i], f1 = ft[t1c][i];
            float4 wq4 = f4_load(wq + i * E_ + e4);
            float4 wk4 = f4_load(wk + i * E_ + e4);
            aq0 = f4_fma(f0, wq4, aq0); aq1 = f4_fma(f1, wq4, aq1);
            ak0 = f4_fma(f0, wk4, ak0); ak1 = f4_fma(f1, wk4, ak1);
        }
        *(float4*)&bufA[t0][e4] = aq0; *(float4*)&bufB[t0][e4] = ak0;
        if (t1 < T_) { *(float4*)&bufA[t1][e4] = aq1; *(float4*)&bufB[t1][e4] = ak1; }
    }
    __syncthreads();

    // all-head scores
    for (int o = tid; o < H_ * T_ * T_; o += 256) {
        int h = o / (T_ * T_); int r = o % (T_ * T_); int q = r / T_, k = r % T_;
        float s = 0.f;
#pragma unroll
        for (int j = 0; j < 4; ++j)
            s += f4_dot(f4_load(&bufA[q][h * 16 + 4 * j]), f4_load(&bufB[k][h * 16 + 4 * j]));
        sc[h][q][k] = s * 0.25f;
    }
    __syncthreads();
    if (tid < H_ * T_) {
        int h = tid / T_, q = tid % T_;
        float m = -1e30f;
        for (int k = 0; k < T_; ++k) m = fmaxf(m, sc[h][q][k]);
        float sum = 0.f;
        for (int k = 0; k < T_; ++k) { float ex = expf(sc[h][q][k] - m); sc[h][q][k] = ex; sum += ex; }
        float inv = 1.0f / sum;
        for (int k = 0; k < T_; ++k) sc[h][q][k] *= inv;
    }
    __syncthreads();

    // v -> bufA (q dead)
    {
        float4 av0 = f4_load(bv + e4), av1 = av0;
        for (int i = 0; i < E_; ++i) {
            float4 wv4 = f4_load(wv + i * E_ + e4);
            av0 = f4_fma(ft[t0][i], wv4, av0);
            av1 = f4_fma(ft[t1c][i], wv4, av1);
        }
        *(float4*)&bufA[t0][e4] = av0;
        if (t1 < T_) *(float4*)&bufA[t1][e4] = av1;
    }
    __syncthreads();

    // attn output -> bufB (k dead)
    {
        int h = l16 >> 2;
        for (int q = r16; q < T_; q += 16) {
            float4 acc = f4_zero();
#pragma unroll
            for (int k = 0; k < T_; ++k) acc = f4_fma(sc[h][q][k], f4_load(&bufA[k][e4]), acc);
            *(float4*)&bufB[q][e4] = acc;
        }
    }
    __syncthreads();

    // ft += bufB @ Wo + bo
    {
        float4 acc0 = f4_load(bo + e4), acc1 = acc0;
        for (int i = 0; i < E_; ++i) {
            float4 w4 = f4_load(wo + i * E_ + e4);
            acc0 = f4_fma(bufB[t0][i], w4, acc0);
            acc1 = f4_fma(bufB[t1c][i], w4, acc1);
        }
        *(float4*)&ft[t0][e4] = f4_add(acc0, f4_load(&ft[t0][e4]));
        if (t1 < T_) *(float4*)&ft[t1][e4] = f4_add(acc1, f4_load(&ft[t1][e4]));
    }
    __syncthreads();

    if (tid < E_) {
        float m = -1e30f;
        for (int t = 0; t < T_; ++t) m = fmaxf(m, ft[t][tid]);
        tmax[(size_t)nv * E_ + tid] = m;
    }
}

// ---------------------------------------------------------------------------
// Kernel 3: per n — max over V, then FC to 7 classes.
// ---------------------------------------------------------------------------
__global__ void k_pool_fc(const float* __restrict__ tmax,
                          const float* __restrict__ fc_w, const float* __restrict__ fc_b,
                          float* __restrict__ out) {
    int n = blockIdx.x;
    int tid = threadIdx.x;  // 64
    __shared__ float pooled[E_];
    float m = -1e30f;
    for (int v = 0; v < V_; ++v) m = fmaxf(m, tmax[((size_t)n * V_ + v) * E_ + tid]);
    pooled[tid] = m;
    __syncthreads();
    if (tid < NC_) {
        float s = fc_b[tid];
        for (int e = 0; e < E_; ++e) s += pooled[e] * fc_w[e * NC_ + tid];
        out[n * NC_ + tid] = s;
    }
}

extern "C" void kernel_launch(void* const* d_in, const int* in_sizes, int n_in,
                              void* d_out, int out_size, void* d_ws, size_t ws_size,
                              hipStream_t stream) {
    const float* xj        = (const float*)d_in[0];
    const float* xv        = (const float*)d_in[1];
    const float* je_w      = (const float*)d_in[2];
    const float* je_b      = (const float*)d_in[3];
    const float* ve_w      = (const float*)d_in[4];
    const float* ve_b      = (const float*)d_in[5];
    const float* joint_emb = (const float*)d_in[6];
    const float* frame_emb = (const float*)d_in[7];
    const float* proj_w    = (const float*)d_in[8];
    const float* proj_b    = (const float*)d_in[9];
    const float* gcn_w1    = (const float*)d_in[10];
    const float* gcn_b1    = (const float*)d_in[11];
    const float* gcn_w2    = (const float*)d_in[12];
    const float* gcn_b2    = (const float*)d_in[13];
    const float* sa_wq     = (const float*)d_in[14];
    const float* sa_bq     = (const float*)d_in[15];
    const float* sa_wk     = (const float*)d_in[16];
    const float* sa_bk     = (const float*)d_in[17];
    const float* sa_wv     = (const float*)d_in[18];
    const float* sa_bv     = (const float*)d_in[19];
    const float* sa_wo     = (const float*)d_in[20];
    const float* sa_bo     = (const float*)d_in[21];
    const float* ta_wq     = (const float*)d_in[22];
    const float* ta_bq     = (const float*)d_in[23];
    const float* ta_wk     = (const float*)d_in[24];
    const float* ta_bk     = (const float*)d_in[25];
    const float* ta_wv     = (const float*)d_in[26];
    const float* ta_bv     = (const float*)d_in[27];
    const float* ta_wo     = (const float*)d_in[28];
    const float* ta_bo     = (const float*)d_in[29];
    const float* fc_w      = (const float*)d_in[30];
    const float* fc_b      = (const float*)d_in[31];
    float* out = (float*)d_out;

    int N = in_sizes[0] / (C_ * T_ * V_);

    // ws layout (floats): tab[3200] | tmax[N*V*E] | feat1[N*T*V*E]
    float* ws    = (float*)d_ws;
    float* tab   = ws;
    float* tmax  = ws + 3200;
    float* feat1 = tmax + (size_t)N * V_ * E_;

    k_setup<<<1, 64, 0, stream>>>(je_w, je_b, ve_w, ve_b, joint_emb, frame_emb,
                                  proj_w, proj_b, tab);
    k_spatial<<<N * T_, 128, 0, stream>>>(xj, xv, tab,
                                          gcn_w1, gcn_b1, gcn_w2, gcn_b2,
                                          sa_wq, sa_bq, sa_wk, sa_bk,
                                          sa_wv, sa_bv, sa_wo, sa_bo, feat1);
    k_temporal<<<N * V_, 256, 0, stream>>>(feat1,
                                           ta_wq, ta_bq, ta_wk, ta_bk,
                                           ta_wv, ta_bv, ta_wo, ta_bo, tmax);
    k_pool_fc<<<N, 64, 0, stream>>>(tmax, fc_w, fc_b, out);
}

// Round 4
// 1434.040 us; speedup vs baseline: 1.8826x; 1.5832x over previous
//
#include <hip/hip_runtime.h>
#include <math.h>

#define C_ 3
#define T_ 30
#define V_ 14
#define E_ 64
#define H_ 4
#define D_ 16
#define NC_ 7

#define EP_ 68   // padded row stride for [*,E] LDS tiles
#define SCT_ 31  // sc row stride, temporal
#define SCV_ 15  // sc/adj row stride, spatial

__device__ __forceinline__ float4 f4_load(const float* p) {
    return *reinterpret_cast<const float4*>(p);
}
__device__ __forceinline__ float4 f4_zero() { return make_float4(0.f, 0.f, 0.f, 0.f); }
__device__ __forceinline__ float4 f4_add(float4 a, float4 b) {
    return make_float4(a.x + b.x, a.y + b.y, a.z + b.z, a.w + b.w);
}
__device__ __forceinline__ float4 f4_fma(float a, float4 b, float4 c) {
    c.x = fmaf(a, b.x, c.x); c.y = fmaf(a, b.y, c.y);
    c.z = fmaf(a, b.z, c.z); c.w = fmaf(a, b.w, c.w); return c;
}
__device__ __forceinline__ float f4_dot(float4 a, float4 b) {
    return a.x * b.x + a.y * b.y + a.z * b.z + a.w * b.w;
}
__device__ __forceinline__ float4 f4_relu(float4 a) {
    return make_float4(fmaxf(a.x, 0.f), fmaxf(a.y, 0.f), fmaxf(a.z, 0.f), fmaxf(a.w, 0.f));
}

// ---------------------------------------------------------------------------
// Setup: collapse the linear front-end into small tables in ws.
// ---------------------------------------------------------------------------
__global__ void k_setup(const float* __restrict__ je_w, const float* __restrict__ je_b,
                        const float* __restrict__ ve_w, const float* __restrict__ ve_b,
                        const float* __restrict__ joint_emb, const float* __restrict__ frame_emb,
                        const float* __restrict__ proj_w, const float* __restrict__ proj_b,
                        float* __restrict__ tab) {
    int e = threadIdx.x;  // 64 threads
    for (int c = 0; c < C_; ++c) {
        float aj = 0.f, av = 0.f;
        for (int i = 0; i < E_; ++i) {
            float p0 = proj_w[i * E_ + e];
            aj += je_w[c * E_ + i] * p0;
            av += ve_w[c * E_ + i] * p0;
        }
        tab[c * E_ + e] = aj;
        tab[192 + c * E_ + e] = av;
    }
    for (int v = 0; v < V_; ++v) {
        float s = 0.f;
        for (int i = 0; i < E_; ++i) s += joint_emb[v * E_ + i] * proj_w[(64 + i) * E_ + e];
        tab[384 + v * E_ + e] = s;
    }
    float bias = proj_b[e];
    for (int i = 0; i < E_; ++i) bias += (je_b[i] + ve_b[i]) * proj_w[i * E_ + e];
    for (int t = 0; t < T_; ++t) {
        float s = bias;
        for (int i = 0; i < E_; ++i) s += frame_emb[t * E_ + i] * proj_w[(128 + i) * E_ + e];
        tab[1280 + t * E_ + e] = s;
    }
}

// ---------------------------------------------------------------------------
// Kernel 1: ONE WAVE per (n,t) tile. 64 threads = 16 e4-lanes x 4 row-slots.
// Each lane owns rows q = r4+4j (3-4 rows) x float4 e-chunk. Barriers are
// single-wave (free); ~10 independent tiles resident per CU hide latency.
// ---------------------------------------------------------------------------
__global__ __launch_bounds__(64) void k_spatial(
    const float* __restrict__ xj, const float* __restrict__ xv,
    const float* __restrict__ tab,
    const float* __restrict__ w1, const float* __restrict__ b1,
    const float* __restrict__ w2, const float* __restrict__ b2,
    const float* __restrict__ wq, const float* __restrict__ bq,
    const float* __restrict__ wk, const float* __restrict__ bk,
    const float* __restrict__ wv, const float* __restrict__ bv,
    const float* __restrict__ wo, const float* __restrict__ bo,
    float* __restrict__ feat1) {
    int nt = blockIdx.x;
    int n = nt / T_;
    int t = nt % T_;
    int tid = threadIdx.x;      // 0..63
    int l16 = tid & 15;
    int e4 = l16 << 2;
    int r4 = tid >> 4;          // 0..3

    // rows owned: q = r4 + 4j, j=0..3 (q<14)
    int qr[4], qc[4];           // real and clamped row ids
#pragma unroll
    for (int j = 0; j < 4; ++j) {
        qr[j] = r4 + 4 * j;
        qc[j] = (qr[j] < V_) ? qr[j] : 0;
    }

    __shared__ __align__(16) float feat[V_][EP_];
    __shared__ __align__(16) float bufA[V_][EP_];
    __shared__ __align__(16) float bufB[V_][EP_];
    __shared__ float sc[H_][V_][SCV_];
    __shared__ float adj[V_][SCV_];
    __shared__ float xs[2][C_][V_];
    __shared__ float inv_nrm[V_];

    // stage x slices (84 values)
    for (int o = tid; o < 2 * C_ * V_; o += 64) {
        int s = o / (C_ * V_);
        int rem = o % (C_ * V_);
        int c = rem / V_, v = rem % V_;
        const float* src = s ? xv : xj;
        xs[s][c][v] = src[((size_t)(n * C_ + c) * T_ + t) * V_ + v];
    }
    __syncthreads();

    // feat build
    {
        float4 F = f4_load(tab + 1280 + t * E_ + e4);
        float4 AJ[C_], AV[C_];
#pragma unroll
        for (int c = 0; c < C_; ++c) {
            AJ[c] = f4_load(tab + c * E_ + e4);
            AV[c] = f4_load(tab + 192 + c * E_ + e4);
        }
#pragma unroll
        for (int j = 0; j < 4; ++j) {
            int q = qr[j];
            if (q < V_) {
                float4 s = f4_add(F, f4_load(tab + 384 + q * E_ + e4));
#pragma unroll
                for (int c = 0; c < C_; ++c) {
                    s = f4_fma(xs[0][c][q], AJ[c], s);
                    s = f4_fma(xs[1][c][q], AV[c], s);
                }
                *(float4*)&feat[q][e4] = s;
            }
        }
    }
    __syncthreads();

    // row inverse norms (14 lanes)
    if (tid < V_) {
        float ss = 0.f;
#pragma unroll
        for (int j = 0; j < 16; ++j) { float4 f = f4_load(&feat[tid][4 * j]); ss += f4_dot(f, f); }
        inv_nrm[tid] = 1.0f / fmaxf(sqrtf(ss), 1e-12f);
    }
    __syncthreads();

    // adjacency scores (cosine sim), 196 dots over 64 lanes
    for (int o = tid; o < V_ * V_; o += 64) {
        int q = o / V_, k = o % V_;
        float s = 0.f;
#pragma unroll
        for (int j = 0; j < 16; ++j) s += f4_dot(f4_load(&feat[q][4 * j]), f4_load(&feat[k][4 * j]));
        adj[q][k] = s * inv_nrm[q] * inv_nrm[k];
    }
    __syncthreads();
    if (tid < V_) {
        float m = -1e30f;
        for (int k = 0; k < V_; ++k) m = fmaxf(m, adj[tid][k]);
        float sum = 0.f;
        for (int k = 0; k < V_; ++k) { float ex = expf(adj[tid][k] - m); adj[tid][k] = ex; sum += ex; }
        float inv = 1.0f / sum;
        for (int k = 0; k < V_; ++k) adj[tid][k] *= inv;
    }
    __syncthreads();

    // bufA = adj @ feat   (k outer: 1 f4 + 4 scalar ds per k, 16 FMA)
    {
        float4 acc[4] = {f4_zero(), f4_zero(), f4_zero(), f4_zero()};
#pragma unroll
        for (int k = 0; k < V_; ++k) {
            float4 fv = f4_load(&feat[k][e4]);
#pragma unroll
            for (int j = 0; j < 4; ++j) acc[j] = f4_fma(adj[qc[j]][k], fv, acc[j]);
        }
#pragma unroll
        for (int j = 0; j < 4; ++j) if (qr[j] < V_) *(float4*)&bufA[qr[j]][e4] = acc[j];
    }
    __syncthreads();

    // bufB = relu(bufA @ W1 + b1)
    {
        float4 acc[4];
        float4 bb = f4_load(b1 + e4);
#pragma unroll
        for (int j = 0; j < 4; ++j) acc[j] = bb;
        for (int i = 0; i < E_; ++i) {
            float4 w4 = f4_load(w1 + i * E_ + e4);
#pragma unroll
            for (int j = 0; j < 4; ++j) acc[j] = f4_fma(bufA[qc[j]][i], w4, acc[j]);
        }
#pragma unroll
        for (int j = 0; j < 4; ++j) if (qr[j] < V_) *(float4*)&bufB[qr[j]][e4] = f4_relu(acc[j]);
    }
    __syncthreads();

    // feat = bufB @ W2 + b2  (post-GCN = residual base)
    {
        float4 acc[4];
        float4 bb = f4_load(b2 + e4);
#pragma unroll
        for (int j = 0; j < 4; ++j) acc[j] = bb;
        for (int i = 0; i < E_; ++i) {
            float4 w4 = f4_load(w2 + i * E_ + e4);
#pragma unroll
            for (int j = 0; j < 4; ++j) acc[j] = f4_fma(bufB[qc[j]][i], w4, acc[j]);
        }
#pragma unroll
        for (int j = 0; j < 4; ++j) if (qr[j] < V_) *(float4*)&feat[qr[j]][e4] = acc[j];
    }
    __syncthreads();

    // q -> bufA, k -> bufB
    {
        float4 aq[4], ak[4];
        float4 bq4 = f4_load(bq + e4), bk4 = f4_load(bk + e4);
#pragma unroll
        for (int j = 0; j < 4; ++j) { aq[j] = bq4; ak[j] = bk4; }
        for (int i = 0; i < E_; ++i) {
            float4 wq4 = f4_load(wq + i * E_ + e4);
            float4 wk4 = f4_load(wk + i * E_ + e4);
#pragma unroll
            for (int j = 0; j < 4; ++j) {
                float f = feat[qc[j]][i];
                aq[j] = f4_fma(f, wq4, aq[j]);
                ak[j] = f4_fma(f, wk4, ak[j]);
            }
        }
#pragma unroll
        for (int j = 0; j < 4; ++j)
            if (qr[j] < V_) { *(float4*)&bufA[qr[j]][e4] = aq[j]; *(float4*)&bufB[qr[j]][e4] = ak[j]; }
    }
    __syncthreads();

    // per-head scores (784 over 64 lanes)
    for (int o = tid; o < H_ * V_ * V_; o += 64) {
        int h = o / (V_ * V_); int r = o % (V_ * V_); int q = r / V_, k = r % V_;
        float s = 0.f;
#pragma unroll
        for (int j = 0; j < 4; ++j)
            s += f4_dot(f4_load(&bufA[q][h * 16 + 4 * j]), f4_load(&bufB[k][h * 16 + 4 * j]));
        sc[h][q][k] = s * 0.25f;  // 1/sqrt(16)
    }
    __syncthreads();
    if (tid < H_ * V_) {   // 56 lanes
        int h = tid / V_, q = tid % V_;
        float m = -1e30f;
        for (int k = 0; k < V_; ++k) m = fmaxf(m, sc[h][q][k]);
        float sum = 0.f;
        for (int k = 0; k < V_; ++k) { float ex = expf(sc[h][q][k] - m); sc[h][q][k] = ex; sum += ex; }
        float inv = 1.0f / sum;
        for (int k = 0; k < V_; ++k) sc[h][q][k] *= inv;
    }
    __syncthreads();

    // v -> bufA (q dead after scores)
    {
        float4 av[4];
        float4 bv4 = f4_load(bv + e4);
#pragma unroll
        for (int j = 0; j < 4; ++j) av[j] = bv4;
        for (int i = 0; i < E_; ++i) {
            float4 wv4 = f4_load(wv + i * E_ + e4);
#pragma unroll
            for (int j = 0; j < 4; ++j) av[j] = f4_fma(feat[qc[j]][i], wv4, av[j]);
        }
#pragma unroll
        for (int j = 0; j < 4; ++j) if (qr[j] < V_) *(float4*)&bufA[qr[j]][e4] = av[j];
    }
    __syncthreads();

    // attn output -> bufB (k dead)
    {
        int h = l16 >> 2;
        float4 acc[4] = {f4_zero(), f4_zero(), f4_zero(), f4_zero()};
#pragma unroll
        for (int k = 0; k < V_; ++k) {
            float4 v4 = f4_load(&bufA[k][e4]);
#pragma unroll
            for (int j = 0; j < 4; ++j) acc[j] = f4_fma(sc[h][qc[j]][k], v4, acc[j]);
        }
#pragma unroll
        for (int j = 0; j < 4; ++j) if (qr[j] < V_) *(float4*)&bufB[qr[j]][e4] = acc[j];
    }
    __syncthreads();

    // feat1 = feat + bufB @ Wo + bo
    {
        float4 acc[4];
        float4 bo4 = f4_load(bo + e4);
#pragma unroll
        for (int j = 0; j < 4; ++j) acc[j] = bo4;
        for (int i = 0; i < E_; ++i) {
            float4 w4 = f4_load(wo + i * E_ + e4);
#pragma unroll
            for (int j = 0; j < 4; ++j) acc[j] = f4_fma(bufB[qc[j]][i], w4, acc[j]);
        }
#pragma unroll
        for (int j = 0; j < 4; ++j)
            if (qr[j] < V_) {
                float4 r = f4_add(acc[j], f4_load(&feat[qr[j]][e4]));
                *(float4*)(feat1 + (size_t)nt * (V_ * E_) + qr[j] * E_ + e4) = r;
            }
    }
}

// ---------------------------------------------------------------------------
// Kernel 2: per (n,v). Temporal MHSA over T + residual, then max over T.
// 256 threads: rows {r16, r16+16} x float4 e-chunk per thread.
// ---------------------------------------------------------------------------
__global__ __launch_bounds__(256) void k_temporal(
    const float* __restrict__ feat1,
    const float* __restrict__ wq, const float* __restrict__ bq,
    const float* __restrict__ wk, const float* __restrict__ bk,
    const float* __restrict__ wv, const float* __restrict__ bv,
    const float* __restrict__ wo, const float* __restrict__ bo,
    float* __restrict__ tmax) {
    int nv = blockIdx.x;
    int n = nv / V_;
    int v = nv % V_;
    int tid = threadIdx.x;
    int l16 = tid & 15;
    int e4 = l16 << 2;
    int r16 = tid >> 4;         // 0..15
    int t0 = r16, t1 = r16 + 16;
    int t1c = (t1 < T_) ? t1 : 0;

    __shared__ __align__(16) float ft[T_][EP_];
    __shared__ __align__(16) float bufA[T_][EP_];
    __shared__ __align__(16) float bufB[T_][EP_];
    __shared__ float sc[H_][T_][SCT_];

    for (int o = tid; o < T_ * 16; o += 256) {
        int tt = o >> 4, l = o & 15;
        *(float4*)&ft[tt][4 * l] =
            f4_load(feat1 + (((size_t)n * T_ + tt) * V_ + v) * E_ + 4 * l);
    }
    __syncthreads();

    // q -> bufA, k -> bufB
    {
        float4 aq0 = f4_load(bq + e4), aq1 = aq0;
        float4 ak0 = f4_load(bk + e4), ak1 = ak0;
        for (int i = 0; i < E_; ++i) {
            float f0 = ft[t0][i], f1 = ft[t1c][i];
            float4 wq4 = f4_load(wq + i * E_ + e4);
            float4 wk4 = f4_load(wk + i * E_ + e4);
            aq0 = f4_fma(f0, wq4, aq0); aq1 = f4_fma(f1, wq4, aq1);
            ak0 = f4_fma(f0, wk4, ak0); ak1 = f4_fma(f1, wk4, ak1);
        }
        *(float4*)&bufA[t0][e4] = aq0; *(float4*)&bufB[t0][e4] = ak0;
        if (t1 < T_) { *(float4*)&bufA[t1][e4] = aq1; *(float4*)&bufB[t1][e4] = ak1; }
    }
    __syncthreads();

    // all-head scores
    for (int o = tid; o < H_ * T_ * T_; o += 256) {
        int h = o / (T_ * T_); int r = o % (T_ * T_); int q = r / T_, k = r % T_;
        float s = 0.f;
#pragma unroll
        for (int j = 0; j < 4; ++j)
            s += f4_dot(f4_load(&bufA[q][h * 16 + 4 * j]), f4_load(&bufB[k][h * 16 + 4 * j]));
        sc[h][q][k] = s * 0.25f;
    }
    __syncthreads();
    if (tid < H_ * T_) {
        int h = tid / T_, q = tid % T_;
        float m = -1e30f;
        for (int k = 0; k < T_; ++k) m = fmaxf(m, sc[h][q][k]);
        float sum = 0.f;
        for (int k = 0; k < T_; ++k) { float ex = expf(sc[h][q][k] - m); sc[h][q][k] = ex; sum += ex; }
        float inv = 1.0f / sum;
        for (int k = 0; k < T_; ++k) sc[h][q][k] *= inv;
    }
    __syncthreads();

    // v -> bufA (q dead)
    {
        float4 av0 = f4_load(bv + e4), av1 = av0;
        for (int i = 0; i < E_; ++i) {
            float4 wv4 = f4_load(wv + i * E_ + e4);
            av0 = f4_fma(ft[t0][i], wv4, av0);
            av1 = f4_fma(ft[t1c][i], wv4, av1);
        }
        *(float4*)&bufA[t0][e4] = av0;
        if (t1 < T_) *(float4*)&bufA[t1][e4] = av1;
    }
    __syncthreads();

    // attn output -> bufB (k dead)
    {
        int h = l16 >> 2;
        for (int q = r16; q < T_; q += 16) {
            float4 acc = f4_zero();
#pragma unroll
            for (int k = 0; k < T_; ++k) acc = f4_fma(sc[h][q][k], f4_load(&bufA[k][e4]), acc);
            *(float4*)&bufB[q][e4] = acc;
        }
    }
    __syncthreads();

    // ft += bufB @ Wo + bo
    {
        float4 acc0 = f4_load(bo + e4), acc1 = acc0;
        for (int i = 0; i < E_; ++i) {
            float4 w4 = f4_load(wo + i * E_ + e4);
            acc0 = f4_fma(bufB[t0][i], w4, acc0);
            acc1 = f4_fma(bufB[t1c][i], w4, acc1);
        }
        *(float4*)&ft[t0][e4] = f4_add(acc0, f4_load(&ft[t0][e4]));
        if (t1 < T_) *(float4*)&ft[t1][e4] = f4_add(acc1, f4_load(&ft[t1][e4]));
    }
    __syncthreads();

    if (tid < E_) {
        float m = -1e30f;
        for (int t = 0; t < T_; ++t) m = fmaxf(m, ft[t][tid]);
        tmax[(size_t)nv * E_ + tid] = m;
    }
}

// ---------------------------------------------------------------------------
// Kernel 3: per n — max over V, then FC to 7 classes.
// ---------------------------------------------------------------------------
__global__ void k_pool_fc(const float* __restrict__ tmax,
                          const float* __restrict__ fc_w, const float* __restrict__ fc_b,
                          float* __restrict__ out) {
    int n = blockIdx.x;
    int tid = threadIdx.x;  // 64
    __shared__ float pooled[E_];
    float m = -1e30f;
    for (int v = 0; v < V_; ++v) m = fmaxf(m, tmax[((size_t)n * V_ + v) * E_ + tid]);
    pooled[tid] = m;
    __syncthreads();
    if (tid < NC_) {
        float s = fc_b[tid];
        for (int e = 0; e < E_; ++e) s += pooled[e] * fc_w[e * NC_ + tid];
        out[n * NC_ + tid] = s;
    }
}

extern "C" void kernel_launch(void* const* d_in, const int* in_sizes, int n_in,
                              void* d_out, int out_size, void* d_ws, size_t ws_size,
                              hipStream_t stream) {
    const float* xj        = (const float*)d_in[0];
    const float* xv        = (const float*)d_in[1];
    const float* je_w      = (const float*)d_in[2];
    const float* je_b      = (const float*)d_in[3];
    const float* ve_w      = (const float*)d_in[4];
    const float* ve_b      = (const float*)d_in[5];
    const float* joint_emb = (const float*)d_in[6];
    const float* frame_emb = (const float*)d_in[7];
    const float* proj_w    = (const float*)d_in[8];
    const float* proj_b    = (const float*)d_in[9];
    const float* gcn_w1    = (const float*)d_in[10];
    const float* gcn_b1    = (const float*)d_in[11];
    const float* gcn_w2    = (const float*)d_in[12];
    const float* gcn_b2    = (const float*)d_in[13];
    const float* sa_wq     = (const float*)d_in[14];
    const float* sa_bq     = (const float*)d_in[15];
    const float* sa_wk     = (const float*)d_in[16];
    const float* sa_bk     = (const float*)d_in[17];
    const float* sa_wv     = (const float*)d_in[18];
    const float* sa_bv     = (const float*)d_in[19];
    const float* sa_wo     = (const float*)d_in[20];
    const float* sa_bo     = (const float*)d_in[21];
    const float* ta_wq     = (const float*)d_in[22];
    const float* ta_bq     = (const float*)d_in[23];
    const float* ta_wk     = (const float*)d_in[24];
    const float* ta_bk     = (const float*)d_in[25];
    const float* ta_wv     = (const float*)d_in[26];
    const float* ta_bv     = (const float*)d_in[27];
    const float* ta_wo     = (const float*)d_in[28];
    const float* ta_bo     = (const float*)d_in[29];
    const float* fc_w      = (const float*)d_in[30];
    const float* fc_b      = (const float*)d_in[31];
    float* out = (float*)d_out;

    int N = in_sizes[0] / (C_ * T_ * V_);

    // ws layout (floats): tab[3200] | tmax[N*V*E] | feat1[N*T*V*E]
    float* ws    = (float*)d_ws;
    float* tab   = ws;
    float* tmax  = ws + 3200;
    float* feat1 = tmax + (size_t)N * V_ * E_;

    k_setup<<<1, 64, 0, stream>>>(je_w, je_b, ve_w, ve_b, joint_emb, frame_emb,
                                  proj_w, proj_b, tab);
    k_spatial<<<N * T_, 64, 0, stream>>>(xj, xv, tab,
                                         gcn_w1, gcn_b1, gcn_w2, gcn_b2,
                                         sa_wq, sa_bq, sa_wk, sa_bk,
                                         sa_wv, sa_bv, sa_wo, sa_bo, feat1);
    k_temporal<<<N * V_, 256, 0, stream>>>(feat1,
                                           ta_wq, ta_bq, ta_wk, ta_bk,
                                           ta_wv, ta_bv, ta_wo, ta_bo, tmax);
    k_pool_fc<<<N, 64, 0, stream>>>(tmax, fc_w, fc_b, out);
}